// Round 1
// baseline (647.102 us; speedup 1.0000x reference)
//
#include <hip/hip_runtime.h>
#include <hip/hip_bf16.h>

#define NN 8192
#define HIDD 128
#define TASKD 64
#define NLAY 2

typedef __attribute__((ext_vector_type(8))) short bf16x8;
typedef __attribute__((ext_vector_type(4))) float f32x4;

static __device__ __forceinline__ unsigned short f2b(float x) {
    __hip_bfloat16 h = __float2bfloat16(x);
    return *reinterpret_cast<unsigned short*>(&h);
}

// ---------------------------------------------------------------- bitmask
__global__ void k_bitmask(const int* __restrict__ adj, unsigned long long* __restrict__ bm) {
    const long total = (long)NN * NN / 64;
    long gw = ((long)blockIdx.x * blockDim.x + threadIdx.x) >> 6;
    int lane = threadIdx.x & 63;
    long nw = ((long)gridDim.x * blockDim.x) >> 6;
    for (long w = gw; w < total; w += nw) {
        int v = adj[w * 64 + lane];
        unsigned long long b = __ballot(v > 0);
        if (lane == 0) bm[w] = b;
    }
}

// ---------------------------------------------------------------- weight prep
// wka[l][r] = sum_c Wk[l][r][c]*a1[l][c]; scal[l*2+0]=bk.a1, scal[l*2+1]=bq.a2
__global__ void k_wprep(const float* __restrict__ Wk, const float* __restrict__ Wq,
                        const float* __restrict__ a1, const float* __restrict__ a2,
                        const float* __restrict__ bk, const float* __restrict__ bq,
                        float* __restrict__ wka, float* __restrict__ wqa,
                        float* __restrict__ scal) {
    int t = threadIdx.x;
    int l = t >> 7, r = t & 127;
    const float* WkL = Wk + (size_t)l * 128 * 128;
    const float* WqL = Wq + (size_t)l * 128 * 128;
    const float* a1L = a1 + l * 128;
    const float* a2L = a2 + l * 128;
    float s1 = 0.f, s2 = 0.f;
    for (int c = 0; c < 128; c++) {
        s1 += WkL[r * 128 + c] * a1L[c];
        s2 += WqL[r * 128 + c] * a2L[c];
    }
    wka[l * 128 + r] = s1;
    wqa[l * 128 + r] = s2;
    if (r == 0) {
        float sb = 0.f, sq = 0.f;
        for (int c = 0; c < 128; c++) {
            sb += bk[l * 128 + c] * a1L[c];
            sq += bq[l * 128 + c] * a2L[c];
        }
        scal[l * 2 + 0] = sb;
        scal[l * 2 + 1] = sq;
    }
}

// ---------------------------------------------------------------- h0 = h @ Wp + bp
__global__ void k_proj(const float* __restrict__ hin, const float* __restrict__ Wp,
                       const float* __restrict__ bp, float* __restrict__ hout) {
    __shared__ float ht[32][128];
    int i0 = blockIdx.x * 32;
    int tid = threadIdx.x;
#pragma unroll
    for (int r = 0; r < 16; r++) {
        int idx = r * 256 + tid;
        ht[idx >> 7][idx & 127] = hin[(size_t)i0 * 128 + idx];
    }
    __syncthreads();
    int c = tid & 127, half = tid >> 7;
    for (int n = half; n < 32; n += 2) {
        float acc = bp[c];
#pragma unroll 8
        for (int k = 0; k < 128; k++) acc = fmaf(ht[n][k], Wp[k * 128 + c], acc);
        hout[(size_t)(i0 + n) * 128 + c] = acc;
    }
}

// ---------------------------------------------------------------- gm = sigmoid([h,z]@Wg+bg) * relu(h@Wm+bm); loss += sum(gate)
__global__ void k_gm(const float* __restrict__ h, const float* __restrict__ z,
                     const float* __restrict__ Wm, const float* __restrict__ bmv,
                     const float* __restrict__ Wg, const float* __restrict__ bgv,
                     float* __restrict__ gm, float* __restrict__ lossacc) {
    __shared__ float ht[32][128];
    __shared__ float zt[32][64];
    __shared__ float red[4];
    int i0 = blockIdx.x * 32;
    int tid = threadIdx.x;
#pragma unroll
    for (int r = 0; r < 16; r++) {
        int idx = r * 256 + tid;
        ht[idx >> 7][idx & 127] = h[(size_t)i0 * 128 + idx];
    }
#pragma unroll
    for (int r = 0; r < 8; r++) {
        int idx = r * 256 + tid;
        zt[idx >> 6][idx & 63] = z[(size_t)i0 * 64 + idx];
    }
    __syncthreads();
    int c = tid & 127, half = tid >> 7;
    float lsum = 0.f;
    for (int n = half; n < 32; n += 2) {
        float am = bmv[c], ag = bgv[c];
#pragma unroll 8
        for (int k = 0; k < 128; k++) am = fmaf(ht[n][k], Wm[k * 128 + c], am);
#pragma unroll 8
        for (int k = 0; k < 128; k++) ag = fmaf(ht[n][k], Wg[k * 128 + c], ag);
#pragma unroll 8
        for (int k = 0; k < 64; k++) ag = fmaf(zt[n][k], Wg[(128 + k) * 128 + c], ag);
        float gate = 1.f / (1.f + __expf(-ag));
        gm[(size_t)(i0 + n) * 128 + c] = gate * fmaxf(am, 0.f);
        lsum += gate;
    }
#pragma unroll
    for (int o = 32; o; o >>= 1) lsum += __shfl_down(lsum, o);
    if ((tid & 63) == 0) red[tid >> 6] = lsum;
    __syncthreads();
    if (tid == 0) atomicAdd(lossacc, red[0] + red[1] + red[2] + red[3]);
}

// ---------------------------------------------------------------- kdot = h@wka + bk.a1 ; qdot = gm@wqa + bq.a2
__global__ void k_dots(const float* __restrict__ h, const float* __restrict__ gm,
                       const float* __restrict__ wka, const float* __restrict__ wqa,
                       const float* __restrict__ scal, float* __restrict__ kdot,
                       float* __restrict__ qdot) {
    int row = (int)((blockIdx.x * blockDim.x + threadIdx.x) >> 6);
    int lane = threadIdx.x & 63;
    const float* hr = h + (size_t)row * 128;
    const float* gr = gm + (size_t)row * 128;
    float s1 = hr[lane] * wka[lane] + hr[lane + 64] * wka[lane + 64];
    float s2 = gr[lane] * wqa[lane] + gr[lane + 64] * wqa[lane + 64];
#pragma unroll
    for (int o = 32; o; o >>= 1) {
        s1 += __shfl_down(s1, o);
        s2 += __shfl_down(s2, o);
    }
    if (lane == 0) {
        kdot[row] = s1 + scal[0];
        qdot[row] = s2 + scal[1];
    }
}

// ---------------------------------------------------------------- coef[i] = 1 / sum_j mask * exp(lrelu(kdot[j]+qdot[i]))
__global__ void k_stats(const unsigned* __restrict__ bm32, const float* __restrict__ kdot,
                        const float* __restrict__ qdot, float* __restrict__ coef) {
    int row = (int)((blockIdx.x * blockDim.x + threadIdx.x) >> 6);
    int lane = threadIdx.x & 63;
    const unsigned* bmr = bm32 + (size_t)row * 256;
    float qi = qdot[row];
    float s = 0.f;
    for (int j = lane; j < NN; j += 64) {
        unsigned word = bmr[j >> 5];
        float e = kdot[j] + qi;
        float f = fmaxf(e, 0.01f * e) * 1.44269504f;
        float t = exp2f(f);
        s += ((word >> (j & 31)) & 1) ? t : 0.f;
    }
#pragma unroll
    for (int o = 32; o; o >>= 1) s += __shfl_xor(s, o);
    if (lane == 0) coef[row] = (s > 0.f) ? 1.0f / s : 0.f;
}

// ---------------------------------------------------------------- gmT[h][i] = bf16(gm[i][h] * coef[i])  (transposed for MFMA B^T layout)
__global__ void k_scale_t(const float* __restrict__ gm, const float* __restrict__ coef,
                          unsigned short* __restrict__ gmT) {
    __shared__ unsigned short t[128][66];
    int i0 = blockIdx.x * 64;
    int tid = threadIdx.x;
#pragma unroll 4
    for (int r = 0; r < 32; r++) {
        int idx = r * 256 + tid;
        int i = idx >> 7, hh = idx & 127;
        float v = gm[(size_t)(i0 + i) * 128 + hh] * coef[i0 + i];
        t[hh][i] = f2b(v);
    }
    __syncthreads();
#pragma unroll 4
    for (int r = 0; r < 32; r++) {
        int idx = r * 256 + tid;
        int hh = idx >> 6, i = idx & 63;
        gmT[(size_t)hh * NN + i0 + i] = t[hh][i];
    }
}

// ---------------------------------------------------------------- pass B: agg[j,:] += sum_i mask*exp(lrelu(kd[j]+qd[i])) * gmT[:,i]
#define BJ 128
#define KC 64
#define NSPLIT 8

__launch_bounds__(256, 2)
__global__ void k_attn_gemm(const unsigned* __restrict__ bm32, const float* __restrict__ kdot,
                            const float* __restrict__ qdot, const unsigned short* __restrict__ gmT,
                            float* __restrict__ dst, int use_atomic) {
    int jb = blockIdx.x;
    int sp = blockIdx.y;
    int j0 = jb * BJ;
    int ibase = sp * (NN / NSPLIT);
    int tid = threadIdx.x;
    int lane = tid & 63;
    int w = tid >> 6;

    __shared__ __align__(16) unsigned short A_l[BJ * KC];   // swizzled [j][i]
    __shared__ __align__(16) unsigned short G_l[HIDD * KC]; // swizzled [h][i]
    __shared__ unsigned mask_l[4 * KC];                     // [jq][i]
    __shared__ float kdot_l[BJ];

    if (tid < BJ) kdot_l[tid] = kdot[j0 + tid];

    f32x4 acc[2][8];
#pragma unroll
    for (int a = 0; a < 2; a++)
#pragma unroll
        for (int b = 0; b < 8; b++) acc[a][b] = (f32x4){0.f, 0.f, 0.f, 0.f};

    int jq0 = j0 >> 5;
    for (int ic = 0; ic < NN / NSPLIT; ic += KC) {
        int ig0 = ibase + ic;
        __syncthreads();  // previous MFMA done reading LDS
        {   // stage mask words: [jq][i]
            int jq = tid >> 6, ii = tid & 63;
            mask_l[jq * KC + ii] = bm32[(size_t)(ig0 + ii) * 256 + jq0 + jq];
        }
        // stage gmT chunk: 1024 x 16B slots, swizzled
#pragma unroll
        for (int r = 0; r < 4; r++) {
            int q = r * 256 + tid;
            int hh = q >> 3, s = q & 7;
            int4 v = *(const int4*)(gmT + (size_t)hh * NN + ig0 + s * 8);
            *(int4*)&G_l[hh * KC + ((s ^ (hh & 7)) * 8)] = v;
        }
        float qv = qdot[ig0 + lane];
        __syncthreads();  // staged data visible
        // A-fill: rep -> j = rep*4 + wave, i = lane
#pragma unroll 8
        for (int rep = 0; rep < 32; rep++) {
            int j = rep * 4 + w;
            unsigned word = mask_l[(j >> 5) * KC + lane];
            float e = kdot_l[j] + qv;
            float f = fmaxf(e, 0.01f * e) * 1.44269504f;
            float wv = exp2f(f);
            if (!((word >> (j & 31)) & 1)) wv = 0.f;
            A_l[j * KC + (lane ^ ((j & 7) << 3))] = f2b(wv);
        }
        __syncthreads();  // A ready
#pragma unroll
        for (int kk = 0; kk < 2; kk++) {
            int kb = kk * 32 + (lane >> 4) * 8;
            int r0 = w * 32 + (lane & 15);
            int r1 = r0 + 16;
            bf16x8 a0 = *(const bf16x8*)&A_l[r0 * KC + (kb ^ ((r0 & 7) << 3))];
            bf16x8 a1v = *(const bf16x8*)&A_l[r1 * KC + (kb ^ ((r1 & 7) << 3))];
#pragma unroll
            for (int hf = 0; hf < 8; hf++) {
                int hr = hf * 16 + (lane & 15);
                bf16x8 bv = *(const bf16x8*)&G_l[hr * KC + (kb ^ ((hr & 7) << 3))];
                acc[0][hf] = __builtin_amdgcn_mfma_f32_16x16x32_bf16(a0, bv, acc[0][hf], 0, 0, 0);
                acc[1][hf] = __builtin_amdgcn_mfma_f32_16x16x32_bf16(a1v, bv, acc[1][hf], 0, 0, 0);
            }
        }
    }
    // epilogue: C/D layout col=lane&15, row=(lane>>4)*4+r
    int row_base = w * 32 + (lane >> 4) * 4;
    int col = lane & 15;
    size_t slab = use_atomic ? 0 : (size_t)sp * NN * HIDD;
#pragma unroll
    for (int jf = 0; jf < 2; jf++)
#pragma unroll
        for (int hf = 0; hf < 8; hf++)
#pragma unroll
            for (int r = 0; r < 4; r++) {
                int j = j0 + row_base + jf * 16 + r;
                int hcol = hf * 16 + col;
                size_t off = (size_t)j * HIDD + hcol;
                if (use_atomic) atomicAdd(&dst[off], acc[jf][hf][r]);
                else dst[slab + off] = acc[jf][hf][r];
            }
}

// ---------------------------------------------------------------- h = (agg + h) * 0.5
__global__ void k_combine(const float* __restrict__ acc, int nslab,
                          const float* __restrict__ hin, float* __restrict__ hout) {
    size_t i = (size_t)blockIdx.x * blockDim.x + threadIdx.x;  // float4 index
    float4 hv = ((const float4*)hin)[i];
    float sx = 0.f, sy = 0.f, sz = 0.f, sw = 0.f;
    for (int s = 0; s < nslab; s++) {
        float4 a = ((const float4*)(acc + (size_t)s * NN * HIDD))[i];
        sx += a.x; sy += a.y; sz += a.z; sw += a.w;
    }
    float4 o;
    o.x = (sx + hv.x) * 0.5f;
    o.y = (sy + hv.y) * 0.5f;
    o.z = (sz + hv.z) * 0.5f;
    o.w = (sw + hv.w) * 0.5f;
    ((float4*)hout)[i] = o;
}

__global__ void k_loss(const float* __restrict__ lossacc, float* __restrict__ out) {
    if (threadIdx.x == 0) out[0] = lossacc[0] / (float)((size_t)NN * HIDD * NLAY);
}

// ================================================================ host
extern "C" void kernel_launch(void* const* d_in, const int* in_sizes, int n_in,
                              void* d_out, int out_size, void* d_ws, size_t ws_size,
                              hipStream_t stream) {
    const float* h_in = (const float*)d_in[0];
    const int* adj = (const int*)d_in[1];
    const float* z = (const float*)d_in[2];
    const float* Wp = (const float*)d_in[3];
    const float* bp = (const float*)d_in[4];
    const float* Wm = (const float*)d_in[5];
    const float* bmv = (const float*)d_in[6];
    const float* Wg = (const float*)d_in[7];
    const float* bgv = (const float*)d_in[8];
    const float* Wk = (const float*)d_in[9];
    const float* bk = (const float*)d_in[10];
    const float* Wq = (const float*)d_in[11];
    const float* bq = (const float*)d_in[12];
    const float* a1 = (const float*)d_in[13];
    const float* a2 = (const float*)d_in[14];
    float* out = (float*)d_out;

    char* ws = (char*)d_ws;
    unsigned long long* BM64 = (unsigned long long*)(ws + 0);          // 8 MB
    unsigned* BM32 = (unsigned*)(ws + 0);
    float* hcur = (float*)(ws + (8ull << 20));                         // 4 MB
    float* gm = (float*)(ws + (12ull << 20));                          // 4 MB
    unsigned short* gmT = (unsigned short*)(ws + (16ull << 20));       // 2 MB
    float* kdot = (float*)(ws + (18ull << 20));                        // 32 KB
    float* qdot = (float*)(ws + (18ull << 20) + (32ull << 10));
    float* coef = (float*)(ws + (18ull << 20) + (64ull << 10));
    float* wka = (float*)(ws + (18ull << 20) + (96ull << 10));
    float* wqa = (float*)(ws + (18ull << 20) + (100ull << 10));
    float* scal = (float*)(ws + (18ull << 20) + (104ull << 10));
    float* lossacc = (float*)(ws + (18ull << 20) + (108ull << 10));
    float* agg = (float*)(ws + (19ull << 20));                         // 4 MB
    float* part = (float*)(ws + (23ull << 20));                        // 8 x 4 MB
    int use_atomic = (ws_size < (56ull << 20)) ? 1 : 0;

    hipMemsetAsync(lossacc, 0, 4, stream);
    k_bitmask<<<2048, 256, 0, stream>>>(adj, BM64);
    k_wprep<<<1, 256, 0, stream>>>(Wk, Wq, a1, a2, bk, bq, wka, wqa, scal);
    k_proj<<<NN / 32, 256, 0, stream>>>(h_in, Wp, bp, hcur);

    for (int l = 0; l < NLAY; l++) {
        k_gm<<<NN / 32, 256, 0, stream>>>(hcur, z, Wm + (size_t)l * 128 * 128, bmv + l * 128,
                                          Wg + (size_t)l * 192 * 128, bgv + l * 128, gm, lossacc);
        k_dots<<<NN / 4, 256, 0, stream>>>(hcur, gm, wka + l * 128, wqa + l * 128, scal + l * 2,
                                           kdot, qdot);
        k_stats<<<NN / 4, 256, 0, stream>>>(BM32, kdot, qdot, coef);
        k_scale_t<<<NN / 64, 256, 0, stream>>>(gm, coef, gmT);
        float* dst = use_atomic ? agg : part;
        if (use_atomic) hipMemsetAsync(agg, 0, (size_t)NN * HIDD * 4, stream);
        dim3 g6(NN / BJ, NSPLIT);
        k_attn_gemm<<<g6, 256, 0, stream>>>(BM32, kdot, qdot, gmT, dst, use_atomic);
        float* hout = (l == NLAY - 1) ? out : hcur;
        k_combine<<<NN * HIDD / 4 / 256, 256, 0, stream>>>(dst, use_atomic ? 1 : NSPLIT, hcur, hout);
    }
    k_loss<<<1, 64, 0, stream>>>(lossacc, out + (size_t)NN * HIDD);
}

// Round 2
// 455.896 us; speedup vs baseline: 1.4194x; 1.4194x over previous
//
#include <hip/hip_runtime.h>
#include <hip/hip_bf16.h>

#define NN 8192
#define HIDD 128
#define NLAY 2

typedef __attribute__((ext_vector_type(8))) short bf16x8;
typedef __attribute__((ext_vector_type(4))) float f32x4;

static __device__ __forceinline__ unsigned short f2b(float x) {
    __hip_bfloat16 h = __float2bfloat16(x);
    return *reinterpret_cast<unsigned short*>(&h);
}

// ---------------------------------------------------------------- bitmask
__global__ void k_bitmask(const int* __restrict__ adj, unsigned long long* __restrict__ bm) {
    const long total = (long)NN * NN / 64;
    long gw = ((long)blockIdx.x * blockDim.x + threadIdx.x) >> 6;
    int lane = threadIdx.x & 63;
    long nw = ((long)gridDim.x * blockDim.x) >> 6;
    for (long w = gw; w < total; w += nw) {
        int v = adj[w * 64 + lane];
        unsigned long long b = __ballot(v > 0);
        if (lane == 0) bm[w] = b;
    }
}

// ---------------------------------------------------------------- weight prep
__global__ void k_wprep(const float* __restrict__ Wk, const float* __restrict__ Wq,
                        const float* __restrict__ a1, const float* __restrict__ a2,
                        const float* __restrict__ bk, const float* __restrict__ bq,
                        float* __restrict__ wka, float* __restrict__ wqa,
                        float* __restrict__ scal) {
    int t = threadIdx.x;
    int l = t >> 7, r = t & 127;
    const float* WkL = Wk + (size_t)l * 128 * 128;
    const float* WqL = Wq + (size_t)l * 128 * 128;
    const float* a1L = a1 + l * 128;
    const float* a2L = a2 + l * 128;
    float s1 = 0.f, s2 = 0.f;
    for (int c = 0; c < 128; c++) {
        s1 += WkL[r * 128 + c] * a1L[c];
        s2 += WqL[r * 128 + c] * a2L[c];
    }
    wka[l * 128 + r] = s1;
    wqa[l * 128 + r] = s2;
    if (r == 0) {
        float sb = 0.f, sq = 0.f;
        for (int c = 0; c < 128; c++) {
            sb += bk[l * 128 + c] * a1L[c];
            sq += bq[l * 128 + c] * a2L[c];
        }
        scal[l * 2 + 0] = sb;
        scal[l * 2 + 1] = sq;
    }
}

// ---------------------------------------------------------------- h0 = h @ Wp + bp  (16 rows/block, weight reuse x8)
__global__ void k_proj(const float* __restrict__ hin, const float* __restrict__ Wp,
                       const float* __restrict__ bp, float* __restrict__ hout) {
    __shared__ float ht[16][128];
    int i0 = blockIdx.x * 16;
    int tid = threadIdx.x;
#pragma unroll
    for (int r = 0; r < 2; r++) {
        int q = r * 256 + tid;
        ((float4*)ht)[q] = ((const float4*)(hin + (size_t)i0 * 128))[q];
    }
    __syncthreads();
    int c = tid & 127, half = tid >> 7;
    float acc[8];
    float b0 = bp[c];
#pragma unroll
    for (int m = 0; m < 8; m++) acc[m] = b0;
    for (int k = 0; k < 128; k++) {
        float w = Wp[k * 128 + c];
#pragma unroll
        for (int m = 0; m < 8; m++) acc[m] = fmaf(ht[half + 2 * m][k], w, acc[m]);
    }
#pragma unroll
    for (int m = 0; m < 8; m++) hout[(size_t)(i0 + half + 2 * m) * 128 + c] = acc[m];
}

// ---------------------------------------------------------------- gm = sigmoid([h,z]@Wg+bg) * relu(h@Wm+bm); loss += sum(gate)
__global__ void k_gm(const float* __restrict__ h, const float* __restrict__ z,
                     const float* __restrict__ Wm, const float* __restrict__ bmv,
                     const float* __restrict__ Wg, const float* __restrict__ bgv,
                     float* __restrict__ gm, float* __restrict__ lossacc) {
    __shared__ float ht[16][128];
    __shared__ float zt[16][64];
    __shared__ float red[4];
    int i0 = blockIdx.x * 16;
    int tid = threadIdx.x;
#pragma unroll
    for (int r = 0; r < 2; r++) {
        int q = r * 256 + tid;
        ((float4*)ht)[q] = ((const float4*)(h + (size_t)i0 * 128))[q];
    }
    ((float4*)zt)[tid] = ((const float4*)(z + (size_t)i0 * 64))[tid];
    __syncthreads();
    int c = tid & 127, half = tid >> 7;
    float am[8], ag[8];
    float bm0 = bmv[c], bg0 = bgv[c];
#pragma unroll
    for (int m = 0; m < 8; m++) { am[m] = bm0; ag[m] = bg0; }
    for (int k = 0; k < 128; k++) {
        float wm = Wm[k * 128 + c], wg = Wg[k * 128 + c];
#pragma unroll
        for (int m = 0; m < 8; m++) {
            float hv = ht[half + 2 * m][k];
            am[m] = fmaf(hv, wm, am[m]);
            ag[m] = fmaf(hv, wg, ag[m]);
        }
    }
    for (int k = 0; k < 64; k++) {
        float wg = Wg[(128 + k) * 128 + c];
#pragma unroll
        for (int m = 0; m < 8; m++) ag[m] = fmaf(zt[half + 2 * m][k], wg, ag[m]);
    }
    float lsum = 0.f;
#pragma unroll
    for (int m = 0; m < 8; m++) {
        float gate = 1.f / (1.f + __expf(-ag[m]));
        lsum += gate;
        gm[(size_t)(i0 + half + 2 * m) * 128 + c] = gate * fmaxf(am[m], 0.f);
    }
#pragma unroll
    for (int o = 32; o; o >>= 1) lsum += __shfl_down(lsum, o);
    if ((tid & 63) == 0) red[tid >> 6] = lsum;
    __syncthreads();
    if (tid == 0) atomicAdd(lossacc, red[0] + red[1] + red[2] + red[3]);
}

// ---------------------------------------------------------------- kdot/qdot
__global__ void k_dots(const float* __restrict__ h, const float* __restrict__ gm,
                       const float* __restrict__ wka, const float* __restrict__ wqa,
                       const float* __restrict__ scal, float* __restrict__ kdot,
                       float* __restrict__ qdot) {
    int row = (int)((blockIdx.x * blockDim.x + threadIdx.x) >> 6);
    int lane = threadIdx.x & 63;
    const float* hr = h + (size_t)row * 128;
    const float* gr = gm + (size_t)row * 128;
    float s1 = hr[lane] * wka[lane] + hr[lane + 64] * wka[lane + 64];
    float s2 = gr[lane] * wqa[lane] + gr[lane + 64] * wqa[lane + 64];
#pragma unroll
    for (int o = 32; o; o >>= 1) {
        s1 += __shfl_down(s1, o);
        s2 += __shfl_down(s2, o);
    }
    if (lane == 0) {
        kdot[row] = s1 + scal[0];
        qdot[row] = s2 + scal[1];
    }
}

// ---------------------------------------------------------------- coef[i] = 1/sum_j mask*exp(lrelu(kdot[j]+qdot[i]))
__global__ void k_stats(const unsigned* __restrict__ bm32, const float* __restrict__ kdot,
                        const float* __restrict__ qdot, float* __restrict__ coef) {
    int row = (int)((blockIdx.x * blockDim.x + threadIdx.x) >> 6);
    int lane = threadIdx.x & 63;
    const unsigned* bmr = bm32 + (size_t)row * 256;
    float qi = qdot[row];
    float s = 0.f;
    for (int t = 0; t < 32; t++) {
        int j0 = t * 256 + lane * 4;
        unsigned word = bmr[j0 >> 5];
        float4 kv = *(const float4*)(kdot + j0);
        int b = (lane & 7) * 4;
        float e, f;
        e = kv.x + qi; f = fmaxf(e, 0.01f * e); s += ((word >> (b + 0)) & 1) ? __expf(f) : 0.f;
        e = kv.y + qi; f = fmaxf(e, 0.01f * e); s += ((word >> (b + 1)) & 1) ? __expf(f) : 0.f;
        e = kv.z + qi; f = fmaxf(e, 0.01f * e); s += ((word >> (b + 2)) & 1) ? __expf(f) : 0.f;
        e = kv.w + qi; f = fmaxf(e, 0.01f * e); s += ((word >> (b + 3)) & 1) ? __expf(f) : 0.f;
    }
#pragma unroll
    for (int o = 32; o; o >>= 1) s += __shfl_xor(s, o);
    if (lane == 0) coef[row] = (s > 0.f) ? 1.0f / s : 0.f;
}

// ---------------------------------------------------------------- gmT[h][i] = bf16(gm[i][h] * coef[i])
__global__ void k_scale_t(const float* __restrict__ gm, const float* __restrict__ coef,
                          unsigned short* __restrict__ gmT) {
    __shared__ unsigned short t[128][66];
    int i0 = blockIdx.x * 64;
    int tid = threadIdx.x;
#pragma unroll 4
    for (int r = 0; r < 32; r++) {
        int idx = r * 256 + tid;
        int i = idx >> 7, hh = idx & 127;
        float v = gm[(size_t)(i0 + i) * 128 + hh] * coef[i0 + i];
        t[hh][i] = f2b(v);
    }
    __syncthreads();
#pragma unroll 4
    for (int r = 0; r < 32; r++) {
        int idx = r * 256 + tid;
        int hh = idx >> 6, i = idx & 63;
        gmT[(size_t)hh * NN + i0 + i] = t[hh][i];
    }
}

// ---------------------------------------------------------------- pass B: pipelined masked-weighted GEMM
#define BJ 128
#define KC 64
#define NSPLIT 8
#define NCH ((NN / NSPLIT) / KC)

__launch_bounds__(256, 2)
__global__ void k_attn_gemm(const unsigned* __restrict__ bm32, const float* __restrict__ kdot,
                            const float* __restrict__ qdot, const unsigned short* __restrict__ gmT,
                            float* __restrict__ dst, int use_atomic) {
    int jb = blockIdx.x;
    int sp = blockIdx.y;
    int j0 = jb * BJ;
    int ibase = sp * (NN / NSPLIT);
    int tid = threadIdx.x;
    int lane = tid & 63;
    int w = tid >> 6;

    __shared__ __align__(16) unsigned short A_l[2][BJ * KC];
    __shared__ __align__(16) unsigned short G_l[2][HIDD * KC];
    __shared__ unsigned mask_l[2][256];
    __shared__ float q_l[2][KC];
    __shared__ float kdot_l[BJ];

    if (tid < BJ) kdot_l[tid] = kdot[j0 + tid];

    int jq0 = j0 >> 5;
    int4 greg[4];
    unsigned mreg;
    float qreg;

    // ---- stage chunk 0 directly
    {
        int ig = ibase;
#pragma unroll
        for (int r = 0; r < 4; r++) {
            int slot = r * 256 + tid;
            int hh = slot >> 3, sd = slot & 7;
            greg[r] = *(const int4*)(gmT + (size_t)hh * NN + ig + sd * 8);
        }
        mreg = bm32[(size_t)(ig + lane) * 256 + jq0 + w];
        qreg = qdot[ig + lane];
#pragma unroll
        for (int r = 0; r < 4; r++) {
            int slot = r * 256 + tid;
            int hh = slot >> 3, sd = slot & 7;
            *(int4*)&G_l[0][hh * KC + ((sd ^ (hh & 7)) * 8)] = greg[r];
        }
        mask_l[0][tid] = mreg;
        if (tid < KC) q_l[0][tid] = qreg;
    }
    __syncthreads();

    f32x4 acc[2][8];
#pragma unroll
    for (int a = 0; a < 2; a++)
#pragma unroll
        for (int b = 0; b < 8; b++) acc[a][b] = (f32x4){0.f, 0.f, 0.f, 0.f};

    int cur = 0;
    for (int c = 0; c < NCH; c++) {
        // 1. issue next-chunk global loads (land under A-fill)
        if (c + 1 < NCH) {
            int ig = ibase + (c + 1) * KC;
#pragma unroll
            for (int r = 0; r < 4; r++) {
                int slot = r * 256 + tid;
                int hh = slot >> 3, sd = slot & 7;
                greg[r] = *(const int4*)(gmT + (size_t)hh * NN + ig + sd * 8);
            }
            mreg = bm32[(size_t)(ig + lane) * 256 + jq0 + w];
            qreg = qdot[ig + lane];
        }
        // 2. A-fill chunk c (packed pairs): 128 rows x 32 u32-writes
#pragma unroll 4
        for (int rep = 0; rep < 16; rep++) {
            int idx = rep * 256 + tid;
            int j = idx >> 5;
            int i0 = (idx & 31) * 2;
            uint2 wds = *(const uint2*)&mask_l[cur][(j >> 5) * KC + i0];
            float2 qv = *(const float2*)&q_l[cur][i0];
            float kd = kdot_l[j];
            int bit = j & 31;
            float e0 = kd + qv.x, f0 = fmaxf(e0, 0.01f * e0);
            float e1 = kd + qv.y, f1 = fmaxf(e1, 0.01f * e1);
            float w0 = ((wds.x >> bit) & 1) ? __expf(f0) : 0.f;
            float w1 = ((wds.y >> bit) & 1) ? __expf(f1) : 0.f;
            unsigned pk = ((unsigned)f2b(w1) << 16) | (unsigned)f2b(w0);
            int dcol = (((i0 >> 3) ^ (j & 7)) * 8) | (i0 & 7);
            *(unsigned*)&A_l[cur][j * KC + dcol] = pk;
        }
        __syncthreads();
        // 3. MFMA on chunk c
#pragma unroll
        for (int kk = 0; kk < 2; kk++) {
            int kb = kk * 32 + (lane >> 4) * 8;
            int r0 = w * 32 + (lane & 15);
            int r1 = r0 + 16;
            bf16x8 a0 = *(const bf16x8*)&A_l[cur][r0 * KC + (kb ^ ((r0 & 7) << 3))];
            bf16x8 a1v = *(const bf16x8*)&A_l[cur][r1 * KC + (kb ^ ((r1 & 7) << 3))];
#pragma unroll
            for (int hf = 0; hf < 8; hf++) {
                int hr = hf * 16 + (lane & 15);
                bf16x8 bv = *(const bf16x8*)&G_l[cur][hr * KC + (kb ^ ((hr & 7) << 3))];
                acc[0][hf] = __builtin_amdgcn_mfma_f32_16x16x32_bf16(a0, bv, acc[0][hf], 0, 0, 0);
                acc[1][hf] = __builtin_amdgcn_mfma_f32_16x16x32_bf16(a1v, bv, acc[1][hf], 0, 0, 0);
            }
        }
        // 4. write staged regs into the other buffer (overlaps MFMA drain)
        if (c + 1 < NCH) {
            int nxt = cur ^ 1;
#pragma unroll
            for (int r = 0; r < 4; r++) {
                int slot = r * 256 + tid;
                int hh = slot >> 3, sd = slot & 7;
                *(int4*)&G_l[nxt][hh * KC + ((sd ^ (hh & 7)) * 8)] = greg[r];
            }
            mask_l[nxt][tid] = mreg;
            if (tid < KC) q_l[nxt][tid] = qreg;
        }
        __syncthreads();
        cur ^= 1;
    }
    // epilogue
    int row_base = w * 32 + (lane >> 4) * 4;
    int col = lane & 15;
    size_t slab = use_atomic ? 0 : (size_t)sp * NN * HIDD;
#pragma unroll
    for (int jf = 0; jf < 2; jf++)
#pragma unroll
        for (int hf = 0; hf < 8; hf++)
#pragma unroll
            for (int r = 0; r < 4; r++) {
                int j = j0 + row_base + jf * 16 + r;
                int hcol = hf * 16 + col;
                size_t off = (size_t)j * HIDD + hcol;
                if (use_atomic) atomicAdd(&dst[off], acc[jf][hf][r]);
                else dst[slab + off] = acc[jf][hf][r];
            }
}

// ---------------------------------------------------------------- h = (agg + h) * 0.5 (+ optional loss write)
__global__ void k_combine(const float* __restrict__ acc, int nslab,
                          const float* __restrict__ hin, float* __restrict__ hout,
                          const float* __restrict__ lossacc, float* __restrict__ lossout) {
    size_t i = (size_t)blockIdx.x * blockDim.x + threadIdx.x;  // float4 index
    float4 hv = ((const float4*)hin)[i];
    float sx = 0.f, sy = 0.f, sz = 0.f, sw = 0.f;
    for (int s = 0; s < nslab; s++) {
        float4 a = ((const float4*)(acc + (size_t)s * NN * HIDD))[i];
        sx += a.x; sy += a.y; sz += a.z; sw += a.w;
    }
    float4 o;
    o.x = (sx + hv.x) * 0.5f;
    o.y = (sy + hv.y) * 0.5f;
    o.z = (sz + hv.z) * 0.5f;
    o.w = (sw + hv.w) * 0.5f;
    ((float4*)hout)[i] = o;
    if (lossout != nullptr && i == 0)
        lossout[0] = lossacc[0] * (1.0f / (float)((size_t)NN * HIDD * NLAY));
}

// ================================================================ host
extern "C" void kernel_launch(void* const* d_in, const int* in_sizes, int n_in,
                              void* d_out, int out_size, void* d_ws, size_t ws_size,
                              hipStream_t stream) {
    const float* h_in = (const float*)d_in[0];
    const int* adj = (const int*)d_in[1];
    const float* z = (const float*)d_in[2];
    const float* Wp = (const float*)d_in[3];
    const float* bp = (const float*)d_in[4];
    const float* Wm = (const float*)d_in[5];
    const float* bmv = (const float*)d_in[6];
    const float* Wg = (const float*)d_in[7];
    const float* bgv = (const float*)d_in[8];
    const float* Wk = (const float*)d_in[9];
    const float* bk = (const float*)d_in[10];
    const float* Wq = (const float*)d_in[11];
    const float* bq = (const float*)d_in[12];
    const float* a1 = (const float*)d_in[13];
    const float* a2 = (const float*)d_in[14];
    float* out = (float*)d_out;

    char* ws = (char*)d_ws;
    unsigned long long* BM64 = (unsigned long long*)(ws + 0);          // 8 MB
    unsigned* BM32 = (unsigned*)(ws + 0);
    float* hcur = (float*)(ws + (8ull << 20));                         // 4 MB
    float* gm = (float*)(ws + (12ull << 20));                          // 4 MB
    unsigned short* gmT = (unsigned short*)(ws + (16ull << 20));       // 2 MB
    float* kdot = (float*)(ws + (18ull << 20));
    float* qdot = (float*)(ws + (18ull << 20) + (32ull << 10));
    float* coef = (float*)(ws + (18ull << 20) + (64ull << 10));
    float* wka = (float*)(ws + (18ull << 20) + (96ull << 10));
    float* wqa = (float*)(ws + (18ull << 20) + (100ull << 10));
    float* scal = (float*)(ws + (18ull << 20) + (104ull << 10));
    float* lossacc = (float*)(ws + (18ull << 20) + (108ull << 10));
    float* agg = (float*)(ws + (19ull << 20));                         // 4 MB
    float* part = (float*)(ws + (23ull << 20));                        // 8 x 4 MB
    int use_atomic = (ws_size < (56ull << 20)) ? 1 : 0;

    hipMemsetAsync(lossacc, 0, 4, stream);
    k_bitmask<<<2048, 256, 0, stream>>>(adj, BM64);
    k_wprep<<<1, 256, 0, stream>>>(Wk, Wq, a1, a2, bk, bq, wka, wqa, scal);
    k_proj<<<NN / 16, 256, 0, stream>>>(h_in, Wp, bp, hcur);

    for (int l = 0; l < NLAY; l++) {
        k_gm<<<NN / 16, 256, 0, stream>>>(hcur, z, Wm + (size_t)l * 128 * 128, bmv + l * 128,
                                          Wg + (size_t)l * 192 * 128, bgv + l * 128, gm, lossacc);
        k_dots<<<NN / 4, 256, 0, stream>>>(hcur, gm, wka + l * 128, wqa + l * 128, scal + l * 2,
                                           kdot, qdot);
        k_stats<<<NN / 4, 256, 0, stream>>>(BM32, kdot, qdot, coef);
        k_scale_t<<<NN / 64, 256, 0, stream>>>(gm, coef, gmT);
        float* dst = use_atomic ? agg : part;
        if (use_atomic) hipMemsetAsync(agg, 0, (size_t)NN * HIDD * 4, stream);
        dim3 g6(NN / BJ, NSPLIT);
        k_attn_gemm<<<g6, 256, 0, stream>>>(BM32, kdot, qdot, gmT, dst, use_atomic);
        float* hout = (l == NLAY - 1) ? out : hcur;
        int last = (l == NLAY - 1);
        k_combine<<<NN * HIDD / 4 / 256, 256, 0, stream>>>(
            dst, use_atomic ? 1 : NSPLIT, hcur, hout,
            lossacc, last ? (out + (size_t)NN * HIDD) : nullptr);
    }
}

// Round 3
// 329.412 us; speedup vs baseline: 1.9644x; 1.3840x over previous
//
#include <hip/hip_runtime.h>
#include <hip/hip_bf16.h>

#define NN 8192
#define HIDD 128
#define NLAY 2

typedef __attribute__((ext_vector_type(8))) short bf16x8;
typedef __attribute__((ext_vector_type(4))) float f32x4;

static __device__ __forceinline__ unsigned short f2b(float x) {
    __hip_bfloat16 h = __float2bfloat16(x);
    return *reinterpret_cast<unsigned short*>(&h);
}

// spread bit i -> bit 4i (16-bit input)
static __device__ __forceinline__ unsigned long long spread4(unsigned long long x) {
    x = (x | (x << 24)) & 0x000000ff000000ffULL;
    x = (x | (x << 12)) & 0x000f000f000f000fULL;
    x = (x | (x << 6))  & 0x0303030303030303ULL;
    x = (x | (x << 3))  & 0x1111111111111111ULL;
    return x;
}

// ---------------------------------------------------------------- bitmask (16B/lane)
__global__ void k_bitmask(const int* __restrict__ adj, unsigned long long* __restrict__ bm) {
    const long totalg = (long)NN * (NN / 256);   // groups of 256 elements
    int tid = threadIdx.x, lane = tid & 63, w = tid >> 6;
    long g = (long)blockIdx.x * 4 + w;
    long ng = (long)gridDim.x * 4;
    for (; g < totalg; g += ng) {
        int4 v = ((const int4*)adj)[g * 64 + lane];   // elems g*256 + 4*lane + 0..3
        unsigned long long B0 = __ballot(v.x > 0);
        unsigned long long B1 = __ballot(v.y > 0);
        unsigned long long B2 = __ballot(v.z > 0);
        unsigned long long B3 = __ballot(v.w > 0);
        if (lane < 4) {
            int sh = lane * 16;
            unsigned long long W = spread4((B0 >> sh) & 0xFFFF)
                                 | (spread4((B1 >> sh) & 0xFFFF) << 1)
                                 | (spread4((B2 >> sh) & 0xFFFF) << 2)
                                 | (spread4((B3 >> sh) & 0xFFFF) << 3);
            bm[g * 4 + lane] = W;
        }
    }
}

// ---------------------------------------------------------------- weight prep (parallel)
__global__ void k_wprep(const float* __restrict__ Wk, const float* __restrict__ Wq,
                        const float* __restrict__ a1, const float* __restrict__ a2,
                        const float* __restrict__ bk, const float* __restrict__ bq,
                        float* __restrict__ wka, float* __restrict__ wqa,
                        float* __restrict__ scal) {
    int b = blockIdx.x;           // 256 blocks: l = b>>7, r = b&127
    int l = b >> 7, r = b & 127;
    int lane = threadIdx.x;       // 64
    const float* WkL = Wk + (size_t)l * 16384 + (size_t)r * 128;
    const float* WqL = Wq + (size_t)l * 16384 + (size_t)r * 128;
    const float* a1L = a1 + l * 128;
    const float* a2L = a2 + l * 128;
    float s1 = WkL[lane] * a1L[lane] + WkL[lane + 64] * a1L[lane + 64];
    float s2 = WqL[lane] * a2L[lane] + WqL[lane + 64] * a2L[lane + 64];
#pragma unroll
    for (int o = 32; o; o >>= 1) {
        s1 += __shfl_down(s1, o);
        s2 += __shfl_down(s2, o);
    }
    if (lane == 0) {
        wka[l * 128 + r] = s1;
        wqa[l * 128 + r] = s2;
    }
    if (r == 0) {
        const float* bkL = bk + l * 128;
        const float* bqL = bq + l * 128;
        float s3 = bkL[lane] * a1L[lane] + bkL[lane + 64] * a1L[lane + 64];
        float s4 = bqL[lane] * a2L[lane] + bqL[lane + 64] * a2L[lane + 64];
#pragma unroll
        for (int o = 32; o; o >>= 1) {
            s3 += __shfl_down(s3, o);
            s4 += __shfl_down(s4, o);
        }
        if (lane == 0) {
            scal[l * 2 + 0] = s3;
            scal[l * 2 + 1] = s4;
        }
    }
}

// ---------------------------------------------------------------- h0 = h @ Wp + bp
__global__ void k_proj(const float* __restrict__ hin, const float* __restrict__ Wp,
                       const float* __restrict__ bp, float* __restrict__ hout) {
    __shared__ float ht[16][128];
    int i0 = blockIdx.x * 16;
    int tid = threadIdx.x;
#pragma unroll
    for (int r = 0; r < 2; r++) {
        int q = r * 256 + tid;
        ((float4*)ht)[q] = ((const float4*)(hin + (size_t)i0 * 128))[q];
    }
    __syncthreads();
    int c = tid & 127, half = tid >> 7;
    float acc[8];
    float b0 = bp[c];
#pragma unroll
    for (int m = 0; m < 8; m++) acc[m] = b0;
    for (int k = 0; k < 128; k += 4) {
        float w0 = Wp[k * 128 + c], w1 = Wp[(k + 1) * 128 + c];
        float w2 = Wp[(k + 2) * 128 + c], w3 = Wp[(k + 3) * 128 + c];
#pragma unroll
        for (int m = 0; m < 8; m++) {
            float4 hv = *(const float4*)&ht[half + 2 * m][k];
            acc[m] = fmaf(hv.x, w0, acc[m]);
            acc[m] = fmaf(hv.y, w1, acc[m]);
            acc[m] = fmaf(hv.z, w2, acc[m]);
            acc[m] = fmaf(hv.w, w3, acc[m]);
        }
    }
#pragma unroll
    for (int m = 0; m < 8; m++) hout[(size_t)(i0 + half + 2 * m) * 128 + c] = acc[m];
}

// ---------------------------------------------------------------- gm + loss
__global__ void k_gm(const float* __restrict__ h, const float* __restrict__ z,
                     const float* __restrict__ Wm, const float* __restrict__ bmv,
                     const float* __restrict__ Wg, const float* __restrict__ bgv,
                     float* __restrict__ gm, float* __restrict__ lossacc) {
    __shared__ float ht[16][128];
    __shared__ float zt[16][64];
    __shared__ float red[4];
    int i0 = blockIdx.x * 16;
    int tid = threadIdx.x;
#pragma unroll
    for (int r = 0; r < 2; r++) {
        int q = r * 256 + tid;
        ((float4*)ht)[q] = ((const float4*)(h + (size_t)i0 * 128))[q];
    }
    ((float4*)zt)[tid] = ((const float4*)(z + (size_t)i0 * 64))[tid];
    __syncthreads();
    int c = tid & 127, half = tid >> 7;
    float am[8], ag[8];
    float bm0 = bmv[c], bg0 = bgv[c];
#pragma unroll
    for (int m = 0; m < 8; m++) { am[m] = bm0; ag[m] = bg0; }
    for (int k = 0; k < 128; k += 4) {
        float wm0 = Wm[k * 128 + c], wm1 = Wm[(k + 1) * 128 + c];
        float wm2 = Wm[(k + 2) * 128 + c], wm3 = Wm[(k + 3) * 128 + c];
        float wg0 = Wg[k * 128 + c], wg1 = Wg[(k + 1) * 128 + c];
        float wg2 = Wg[(k + 2) * 128 + c], wg3 = Wg[(k + 3) * 128 + c];
#pragma unroll
        for (int m = 0; m < 8; m++) {
            float4 hv = *(const float4*)&ht[half + 2 * m][k];
            am[m] = fmaf(hv.x, wm0, am[m]);
            am[m] = fmaf(hv.y, wm1, am[m]);
            am[m] = fmaf(hv.z, wm2, am[m]);
            am[m] = fmaf(hv.w, wm3, am[m]);
            ag[m] = fmaf(hv.x, wg0, ag[m]);
            ag[m] = fmaf(hv.y, wg1, ag[m]);
            ag[m] = fmaf(hv.z, wg2, ag[m]);
            ag[m] = fmaf(hv.w, wg3, ag[m]);
        }
    }
    for (int k = 0; k < 64; k += 4) {
        float wg0 = Wg[(128 + k) * 128 + c], wg1 = Wg[(129 + k) * 128 + c];
        float wg2 = Wg[(130 + k) * 128 + c], wg3 = Wg[(131 + k) * 128 + c];
#pragma unroll
        for (int m = 0; m < 8; m++) {
            float4 zv = *(const float4*)&zt[half + 2 * m][k];
            ag[m] = fmaf(zv.x, wg0, ag[m]);
            ag[m] = fmaf(zv.y, wg1, ag[m]);
            ag[m] = fmaf(zv.z, wg2, ag[m]);
            ag[m] = fmaf(zv.w, wg3, ag[m]);
        }
    }
    float lsum = 0.f;
#pragma unroll
    for (int m = 0; m < 8; m++) {
        float gate = 1.f / (1.f + __expf(-ag[m]));
        lsum += gate;
        gm[(size_t)(i0 + half + 2 * m) * 128 + c] = gate * fmaxf(am[m], 0.f);
    }
#pragma unroll
    for (int o = 32; o; o >>= 1) lsum += __shfl_down(lsum, o);
    if ((tid & 63) == 0) red[tid >> 6] = lsum;
    __syncthreads();
    if (tid == 0) atomicAdd(lossacc, red[0] + red[1] + red[2] + red[3]);
}

// ---------------------------------------------------------------- kdot/qdot (pre-scaled by log2 e)
__global__ void k_dots(const float* __restrict__ h, const float* __restrict__ gm,
                       const float* __restrict__ wka, const float* __restrict__ wqa,
                       const float* __restrict__ scal, float* __restrict__ kdot,
                       float* __restrict__ qdot) {
    int row = (int)((blockIdx.x * blockDim.x + threadIdx.x) >> 6);
    int lane = threadIdx.x & 63;
    const float* hr = h + (size_t)row * 128;
    const float* gr = gm + (size_t)row * 128;
    float s1 = hr[lane] * wka[lane] + hr[lane + 64] * wka[lane + 64];
    float s2 = gr[lane] * wqa[lane] + gr[lane + 64] * wqa[lane + 64];
#pragma unroll
    for (int o = 32; o; o >>= 1) {
        s1 += __shfl_down(s1, o);
        s2 += __shfl_down(s2, o);
    }
    if (lane == 0) {
        const float LOG2E = 1.4426950408889634f;
        kdot[row] = (s1 + scal[0]) * LOG2E;
        qdot[row] = (s2 + scal[1]) * LOG2E;
    }
}

// ---------------------------------------------------------------- coef[i] = 1/sum_j mask*exp2(lrelu2(...))
__global__ void k_stats(const unsigned* __restrict__ bm32, const float* __restrict__ kdot,
                        const float* __restrict__ qdot, float* __restrict__ coef) {
    int row = (int)((blockIdx.x * blockDim.x + threadIdx.x) >> 6);
    int lane = threadIdx.x & 63;
    const unsigned* bmr = bm32 + (size_t)row * 256;
    float qi = qdot[row];
    float s = 0.f;
    for (int t = 0; t < 32; t++) {
        int j0 = t * 256 + lane * 4;
        unsigned word = bmr[j0 >> 5];
        float4 kv = *(const float4*)(kdot + j0);
        int b = (lane & 7) * 4;
        float e, f;
        e = kv.x + qi; f = fmaxf(e, 0.01f * e); s += ((word >> (b + 0)) & 1) ? exp2f(f) : 0.f;
        e = kv.y + qi; f = fmaxf(e, 0.01f * e); s += ((word >> (b + 1)) & 1) ? exp2f(f) : 0.f;
        e = kv.z + qi; f = fmaxf(e, 0.01f * e); s += ((word >> (b + 2)) & 1) ? exp2f(f) : 0.f;
        e = kv.w + qi; f = fmaxf(e, 0.01f * e); s += ((word >> (b + 3)) & 1) ? exp2f(f) : 0.f;
    }
#pragma unroll
    for (int o = 32; o; o >>= 1) s += __shfl_xor(s, o);
    if (lane == 0) coef[row] = (s > 0.f) ? 1.0f / s : 0.f;
}

// ---------------------------------------------------------------- gmT[h][i] = bf16(gm[i][h] * coef[i])
__global__ void k_scale_t(const float* __restrict__ gm, const float* __restrict__ coef,
                          unsigned short* __restrict__ gmT) {
    __shared__ unsigned short t[128][66];
    int i0 = blockIdx.x * 64;
    int tid = threadIdx.x;
#pragma unroll 4
    for (int r = 0; r < 32; r++) {
        int idx = r * 256 + tid;
        int i = idx >> 7, hh = idx & 127;
        float v = gm[(size_t)(i0 + i) * 128 + hh] * coef[i0 + i];
        t[hh][i] = f2b(v);
    }
    __syncthreads();
#pragma unroll 4
    for (int r = 0; r < 32; r++) {
        int idx = r * 256 + tid;
        int hh = idx >> 6, i = idx & 63;
        gmT[(size_t)hh * NN + i0 + i] = t[hh][i];
    }
}

// ---------------------------------------------------------------- pass B: pipelined masked-weighted GEMM
#define BJ 128
#define KC 64
#define NSPLIT 8
#define NCH ((NN / NSPLIT) / KC)

__launch_bounds__(256, 2)
__global__ void k_attn_gemm(const unsigned* __restrict__ bm32, const float* __restrict__ kdot,
                            const float* __restrict__ qdot, const unsigned short* __restrict__ gmT,
                            float* __restrict__ dst, int use_atomic) {
    int id = blockIdx.x;
    int sp = id & 7;          // XCD-local i-split: all blocks of one sp share one XCD's L2
    int jb = id >> 3;
    int j0 = jb * BJ;
    int ibase = sp * (NN / NSPLIT);
    int tid = threadIdx.x;
    int lane = tid & 63;
    int w = tid >> 6;

    __shared__ __align__(16) unsigned short A_l[BJ * KC];       // single buffer
    __shared__ __align__(16) unsigned short G_l[2][HIDD * KC];
    __shared__ unsigned mask_l[2][256];
    __shared__ float q_l[2][KC];
    __shared__ float kdot_l[BJ];

    if (tid < BJ) kdot_l[tid] = kdot[j0 + tid];

    int jq0 = j0 >> 5;
    int4 greg[4];
    unsigned mreg;
    float qreg;

    // ---- stage chunk 0 directly
    {
        int ig = ibase;
#pragma unroll
        for (int r = 0; r < 4; r++) {
            int slot = r * 256 + tid;
            int hh = slot >> 3, sd = slot & 7;
            greg[r] = *(const int4*)(gmT + (size_t)hh * NN + ig + sd * 8);
        }
        mreg = bm32[(size_t)(ig + lane) * 256 + jq0 + w];
        qreg = qdot[ig + lane];
#pragma unroll
        for (int r = 0; r < 4; r++) {
            int slot = r * 256 + tid;
            int hh = slot >> 3, sd = slot & 7;
            *(int4*)&G_l[0][hh * KC + ((sd ^ (hh & 7)) * 8)] = greg[r];
        }
        mask_l[0][tid] = mreg;
        if (tid < KC) q_l[0][tid] = qreg;
    }
    __syncthreads();

    f32x4 acc[2][8];
#pragma unroll
    for (int a = 0; a < 2; a++)
#pragma unroll
        for (int b = 0; b < 8; b++) acc[a][b] = (f32x4){0.f, 0.f, 0.f, 0.f};

    int cur = 0;
    for (int c = 0; c < NCH; c++) {
        // 1. issue next-chunk global loads (in flight across fill + mfma)
        if (c + 1 < NCH) {
            int ig = ibase + (c + 1) * KC;
#pragma unroll
            for (int r = 0; r < 4; r++) {
                int slot = r * 256 + tid;
                int hh = slot >> 3, sd = slot & 7;
                greg[r] = *(const int4*)(gmT + (size_t)hh * NN + ig + sd * 8);
            }
            mreg = bm32[(size_t)(ig + lane) * 256 + jq0 + w];
            qreg = qdot[ig + lane];
        }
        // 2. A-fill chunk c (log2-domain, packed pairs)
#pragma unroll 4
        for (int rep = 0; rep < 16; rep++) {
            int idx = rep * 256 + tid;
            int j = idx >> 5;
            int i0 = (idx & 31) * 2;
            uint2 wds = *(const uint2*)&mask_l[cur][(j >> 5) * KC + i0];
            float2 qv = *(const float2*)&q_l[cur][i0];
            float kd = kdot_l[j];
            int bit = j & 31;
            float e0 = kd + qv.x, f0 = fmaxf(e0, 0.01f * e0);
            float e1 = kd + qv.y, f1 = fmaxf(e1, 0.01f * e1);
            float w0 = ((wds.x >> bit) & 1) ? exp2f(f0) : 0.f;
            float w1 = ((wds.y >> bit) & 1) ? exp2f(f1) : 0.f;
            unsigned pk = ((unsigned)f2b(w1) << 16) | (unsigned)f2b(w0);
            int dcol = (((i0 >> 3) ^ (j & 7)) * 8) | (i0 & 7);
            *(unsigned*)&A_l[j * KC + dcol] = pk;
        }
        __syncthreads();   // A ready (G[cur] ready from previous barrier)
        // 3. MFMA on chunk c
        __builtin_amdgcn_s_setprio(1);
#pragma unroll
        for (int kk = 0; kk < 2; kk++) {
            int kb = kk * 32 + (lane >> 4) * 8;
            int r0 = w * 32 + (lane & 15);
            int r1 = r0 + 16;
            bf16x8 a0 = *(const bf16x8*)&A_l[r0 * KC + (kb ^ ((r0 & 7) << 3))];
            bf16x8 a1v = *(const bf16x8*)&A_l[r1 * KC + (kb ^ ((r1 & 7) << 3))];
#pragma unroll
            for (int hf = 0; hf < 8; hf++) {
                int hr = hf * 16 + (lane & 15);
                bf16x8 bv = *(const bf16x8*)&G_l[cur][hr * KC + (kb ^ ((hr & 7) << 3))];
                acc[0][hf] = __builtin_amdgcn_mfma_f32_16x16x32_bf16(a0, bv, acc[0][hf], 0, 0, 0);
                acc[1][hf] = __builtin_amdgcn_mfma_f32_16x16x32_bf16(a1v, bv, acc[1][hf], 0, 0, 0);
            }
        }
        __builtin_amdgcn_s_setprio(0);
        // 4. write staged regs into the other G/mask/q buffer
        if (c + 1 < NCH) {
            int nxt = cur ^ 1;
#pragma unroll
            for (int r = 0; r < 4; r++) {
                int slot = r * 256 + tid;
                int hh = slot >> 3, sd = slot & 7;
                *(int4*)&G_l[nxt][hh * KC + ((sd ^ (hh & 7)) * 8)] = greg[r];
            }
            mask_l[nxt][tid] = mreg;
            if (tid < KC) q_l[nxt][tid] = qreg;
        }
        __syncthreads();   // G[nxt] ready; all reads of A done -> next fill may overwrite
        cur ^= 1;
    }
    // epilogue: C/D layout col=lane&15, row=(lane>>4)*4+r
    int row_base = w * 32 + (lane >> 4) * 4;
    int col = lane & 15;
    size_t slab = use_atomic ? 0 : (size_t)sp * NN * HIDD;
#pragma unroll
    for (int jf = 0; jf < 2; jf++)
#pragma unroll
        for (int hf = 0; hf < 8; hf++)
#pragma unroll
            for (int r = 0; r < 4; r++) {
                int j = j0 + row_base + jf * 16 + r;
                int hcol = hf * 16 + col;
                size_t off = (size_t)j * HIDD + hcol;
                if (use_atomic) atomicAdd(&dst[off], acc[jf][hf][r]);
                else dst[slab + off] = acc[jf][hf][r];
            }
}

// ---------------------------------------------------------------- h = (agg + h) * 0.5 (+ optional loss write)
__global__ void k_combine(const float* __restrict__ acc, int nslab,
                          const float* __restrict__ hin, float* __restrict__ hout,
                          const float* __restrict__ lossacc, float* __restrict__ lossout) {
    size_t i = (size_t)blockIdx.x * blockDim.x + threadIdx.x;  // float4 index
    float4 hv = ((const float4*)hin)[i];
    float sx = 0.f, sy = 0.f, sz = 0.f, sw = 0.f;
    for (int s = 0; s < nslab; s++) {
        float4 a = ((const float4*)(acc + (size_t)s * NN * HIDD))[i];
        sx += a.x; sy += a.y; sz += a.z; sw += a.w;
    }
    float4 o;
    o.x = (sx + hv.x) * 0.5f;
    o.y = (sy + hv.y) * 0.5f;
    o.z = (sz + hv.z) * 0.5f;
    o.w = (sw + hv.w) * 0.5f;
    ((float4*)hout)[i] = o;
    if (lossout != nullptr && i == 0)
        lossout[0] = lossacc[0] * (1.0f / (float)((size_t)NN * HIDD * NLAY));
}

// ================================================================ host
extern "C" void kernel_launch(void* const* d_in, const int* in_sizes, int n_in,
                              void* d_out, int out_size, void* d_ws, size_t ws_size,
                              hipStream_t stream) {
    const float* h_in = (const float*)d_in[0];
    const int* adj = (const int*)d_in[1];
    const float* z = (const float*)d_in[2];
    const float* Wp = (const float*)d_in[3];
    const float* bp = (const float*)d_in[4];
    const float* Wm = (const float*)d_in[5];
    const float* bmv = (const float*)d_in[6];
    const float* Wg = (const float*)d_in[7];
    const float* bgv = (const float*)d_in[8];
    const float* Wk = (const float*)d_in[9];
    const float* bk = (const float*)d_in[10];
    const float* Wq = (const float*)d_in[11];
    const float* bq = (const float*)d_in[12];
    const float* a1 = (const float*)d_in[13];
    const float* a2 = (const float*)d_in[14];
    float* out = (float*)d_out;

    char* ws = (char*)d_ws;
    unsigned long long* BM64 = (unsigned long long*)(ws + 0);          // 8 MB
    unsigned* BM32 = (unsigned*)(ws + 0);
    float* hcur = (float*)(ws + (8ull << 20));                         // 4 MB
    float* gm = (float*)(ws + (12ull << 20));                          // 4 MB
    unsigned short* gmT = (unsigned short*)(ws + (16ull << 20));       // 2 MB
    float* kdot = (float*)(ws + (18ull << 20));
    float* qdot = (float*)(ws + (18ull << 20) + (32ull << 10));
    float* coef = (float*)(ws + (18ull << 20) + (64ull << 10));
    float* wka = (float*)(ws + (18ull << 20) + (96ull << 10));
    float* wqa = (float*)(ws + (18ull << 20) + (100ull << 10));
    float* scal = (float*)(ws + (18ull << 20) + (104ull << 10));
    float* lossacc = (float*)(ws + (18ull << 20) + (108ull << 10));
    float* agg = (float*)(ws + (19ull << 20));                         // 4 MB
    float* part = (float*)(ws + (23ull << 20));                        // 8 x 4 MB
    int use_atomic = (ws_size < (56ull << 20)) ? 1 : 0;

    hipMemsetAsync(lossacc, 0, 4, stream);
    k_bitmask<<<2048, 256, 0, stream>>>(adj, BM64);
    k_wprep<<<256, 64, 0, stream>>>(Wk, Wq, a1, a2, bk, bq, wka, wqa, scal);
    k_proj<<<NN / 16, 256, 0, stream>>>(h_in, Wp, bp, hcur);

    for (int l = 0; l < NLAY; l++) {
        k_gm<<<NN / 16, 256, 0, stream>>>(hcur, z, Wm + (size_t)l * 128 * 128, bmv + l * 128,
                                          Wg + (size_t)l * 192 * 128, bgv + l * 128, gm, lossacc);
        k_dots<<<NN / 4, 256, 0, stream>>>(hcur, gm, wka + l * 128, wqa + l * 128, scal + l * 2,
                                           kdot, qdot);
        k_stats<<<NN / 4, 256, 0, stream>>>(BM32, kdot, qdot, coef);
        k_scale_t<<<NN / 64, 256, 0, stream>>>(gm, coef, gmT);
        float* dst = use_atomic ? agg : part;
        if (use_atomic) hipMemsetAsync(agg, 0, (size_t)NN * HIDD * 4, stream);
        k_attn_gemm<<<(NN / BJ) * NSPLIT, 256, 0, stream>>>(BM32, kdot, qdot, gmT, dst, use_atomic);
        float* hout = (l == NLAY - 1) ? out : hcur;
        int last = (l == NLAY - 1);
        k_combine<<<NN * HIDD / 4 / 256, 256, 0, stream>>>(
            dst, use_atomic ? 1 : NSPLIT, hcur, hout,
            lossacc, last ? (out + (size_t)NN * HIDD) : nullptr);
    }
}